// Round 5
// baseline (402.628 us; speedup 1.0000x reference)
//
#include <hip/hip_runtime.h>
#include <hip/hip_bf16.h>
#include <cstdint>
#include <cstddef>

#define BB 32
#define LL 2048
#define DD 1024
#define HH 16
#define HDIM 64
#define NL 4
#define NCHUNK 8
#define CHUNK 256
#define NEGINF -1e30f

typedef __attribute__((ext_vector_type(8))) short bf16x8;
typedef __attribute__((ext_vector_type(4))) float f32x4;

__device__ __forceinline__ unsigned short f2b(float x) {
    union { float f; unsigned int u; } v; v.f = x;
    unsigned int r = (v.u + 0x7FFFu + ((v.u >> 16) & 1u)) >> 16;
    return (unsigned short)r;
}

// ---------------- split-K GEMV partials: part[ks][b][c] = X[b, e0:e0+KL] @ W[e0:e0+KL, c]
// SRC 0: X[b][e] = Xg[e]                      (broadcast qt)
// SRC 1: X = (Xg - mu)*rstd*gamma + beta      (LayerNorm applied on the fly)
// SRC 2: X = bias + sum_{j2<32} parts_in      (combine pv partials)
// SRC 3: X = sum_c8 wgt[b][c8]*ctx_p[...]     (softmax chunk combine; head = ct)
template<int SRC, int KSP>
__global__ __launch_bounds__(256) void k_gemv(
        const float* __restrict__ Xg,
        const float* __restrict__ stats, const float* __restrict__ gamma,
        const float* __restrict__ beta,
        const float* __restrict__ parts_in, const float* __restrict__ bias_in,
        const float* __restrict__ ctx_p, const float* __restrict__ m_p,
        const float* __restrict__ s_p,
        const float* __restrict__ W, float* __restrict__ outp) {
    constexpr int KL = DD / KSP;
    int bid = blockIdx.x, tid = threadIdx.x;
    int ct = bid & 15, ks = bid >> 4;
    int e0 = ks * KL;
    __shared__ float Xs[BB][KL];
    __shared__ float wgtS[BB][NCHUNK];
    __shared__ float mgS[BB], SgS[BB];
    if (SRC == 3) {
        if (tid < BB) {
            int b = tid; float m = NEGINF;
            for (int c8 = 0; c8 < NCHUNK; ++c8)
                m = fmaxf(m, m_p[(b * NCHUNK + c8) * HH + ct]);
            float S = 0.f;
            for (int c8 = 0; c8 < NCHUNK; ++c8)
                S += s_p[(b * NCHUNK + c8) * HH + ct] *
                     __expf(m_p[(b * NCHUNK + c8) * HH + ct] - m);
            mgS[b] = m; SgS[b] = S;
        }
        __syncthreads();
        {
            int b = tid >> 3, c8 = tid & 7;
            wgtS[b][c8] = __expf(m_p[(b * NCHUNK + c8) * HH + ct] - mgS[b]) / SgS[b];
        }
        __syncthreads();
    }
    // stage Xs[32][KL]
    for (int j = 0; j < (BB * KL) / 256; ++j) {
        int i = tid + j * 256;
        int b = i / KL, k = i % KL;
        float x;
        if (SRC == 0) {
            x = Xg[e0 + k];
        } else if (SRC == 1) {
            float mu = stats[b * 2], rstd = stats[b * 2 + 1];
            x = (Xg[(size_t)b * DD + e0 + k] - mu) * rstd * gamma[e0 + k] + beta[e0 + k];
        } else if (SRC == 2) {
            x = bias_in[e0 + k];
#pragma unroll
            for (int j2 = 0; j2 < 32; ++j2)
                x += parts_in[((size_t)(j2 * BB) + b) * DD + e0 + k];
        } else {
            x = 0.f;
#pragma unroll
            for (int c8 = 0; c8 < NCHUNK; ++c8)
                x += wgtS[b][c8] *
                     ctx_p[(((size_t)(b * NCHUNK + c8)) * HH + ct) * DD + e0 + k];
        }
        Xs[b][k] = x;
    }
    __syncthreads();
    int col = tid & 63, bg = tid >> 6;
    int c = ct * 64 + col;
    float acc[8] = {0.f, 0.f, 0.f, 0.f, 0.f, 0.f, 0.f, 0.f};
    for (int k = 0; k < KL; k += 4) {
        float w0 = W[(size_t)(e0 + k) * DD + c];
        float w1 = W[(size_t)(e0 + k + 1) * DD + c];
        float w2 = W[(size_t)(e0 + k + 2) * DD + c];
        float w3 = W[(size_t)(e0 + k + 3) * DD + c];
#pragma unroll
        for (int bb = 0; bb < 8; ++bb) {
            const float4 xv = *(const float4*)&Xs[bg * 8 + bb][k];
            acc[bb] += xv.x * w0 + xv.y * w1 + xv.z * w2 + xv.w * w3;
        }
    }
#pragma unroll
    for (int bb = 0; bb < 8; ++bb)
        outp[((size_t)(ks * BB) + bg * 8 + bb) * DD + c] = acc[bb];
}

// ---------------- combine o partials (KS=8) + bo -> oraw + LN stats; 32 blocks x 1024
__global__ __launch_bounds__(1024) void k_stats(const float* __restrict__ parts,
        const float* __restrict__ bo, float* __restrict__ oraw,
        float* __restrict__ stats) {
    int b = blockIdx.x, c = threadIdx.x;
    float v = bo[c];
#pragma unroll
    for (int ks = 0; ks < 8; ++ks)
        v += parts[((size_t)(ks * BB) + b) * DD + c];
    oraw[(size_t)b * DD + c] = v;
    float s1 = v, s2 = v * v;
#pragma unroll
    for (int off = 32; off; off >>= 1) {
        s1 += __shfl_xor(s1, off);
        s2 += __shfl_xor(s2, off);
    }
    __shared__ float r1[16], r2[16];
    int w = c >> 6;
    if ((c & 63) == 0) { r1[w] = s1; r2[w] = s2; }
    __syncthreads();
    if (c == 0) {
        float a = 0.f, q = 0.f;
#pragma unroll
        for (int i = 0; i < 16; ++i) { a += r1[i]; q += r2[i]; }
        float mu = a / (float)DD, var = q / (float)DD - mu * mu;
        stats[b * 2] = mu;
        stats[b * 2 + 1] = rsqrtf(var + 1e-5f);
    }
}

// ---------------- final LN apply
__global__ __launch_bounds__(256) void k_final(const float* __restrict__ oraw,
        const float* __restrict__ stats, const float* __restrict__ gamma,
        const float* __restrict__ beta, float* __restrict__ outp) {
    int i = blockIdx.x * 256 + threadIdx.x;
    int b = i >> 10, c = i & (DD - 1);
    outp[i] = (oraw[i] - stats[b * 2]) * stats[b * 2 + 1] * gamma[c] + beta[c];
}

// ---------------- wk[b,h,e] = Wk[e, h*64:+64] . qh[b, h*64:+64] (bf16) + sbuf
// qh combined inline from qp partials (KS=8) + bq. grid 256: h(16) x et(16)
__global__ __launch_bounds__(256) void k_wk(const float* __restrict__ qp,
        const float* __restrict__ bq,
        const float* __restrict__ Wk, const float* __restrict__ bk,
        unsigned short* __restrict__ wk16, float* __restrict__ sb) {
    int h = blockIdx.x >> 4, et = blockIdx.x & 15;
    int tid = threadIdx.x;
    __shared__ float qs[BB][HDIM + 1];
    for (int i = tid; i < BB * HDIM; i += 256) {
        int bb = i >> 6, d = i & 63;
        float v = bq[h * HDIM + d];
#pragma unroll
        for (int ks = 0; ks < 8; ++ks)
            v += qp[((size_t)(ks * BB + bb)) * DD + h * HDIM + d];
        qs[bb][d] = v;
    }
    __syncthreads();
    int b = tid & 31, eo = tid >> 5;   // eo: 0..7
    for (int k = 0; k < 8; ++k) {
        int e = et * 64 + eo * 8 + k;
        const float* wrow = Wk + (size_t)e * DD + h * HDIM;
        float acc = 0.f;
#pragma unroll
        for (int d = 0; d < HDIM; ++d) acc += qs[b][d] * wrow[d];
        wk16[((size_t)(b * HH + h)) * DD + e] = f2b(acc);
    }
    if (et == 0 && tid < BB) {
        float acc = 0.f;
#pragma unroll
        for (int d = 0; d < HDIM; ++d) acc += qs[tid][d] * bk[h * HDIM + d];
        sb[tid * HH + h] = acc;
    }
}

// ---------------- main streaming attention pass (partial per (b, chunk))
// MODE 0: fp32 reads. MODE 1: fp32 reads + bf16 cache write. MODE 2: bf16 cache reads.
// Register-prefetch double buffering: group g+1's global loads issued before
// group g's compute phases; vmcnt wait lands at g+1's LDS write.
template<int MODE>
__global__ __launch_bounds__(1024) void k_attn(const float* __restrict__ toks,
        unsigned short* __restrict__ tcache,
        const int* __restrict__ lens, const unsigned short* __restrict__ wk16,
        const float* __restrict__ sb, float* __restrict__ ctx_p,
        float* __restrict__ m_p, float* __restrict__ s_p) {
    int b = blockIdx.x >> 3, chunk = blockIdx.x & 7;
    int tid = threadIdx.x, lane = tid & 63, w = tid >> 6;
    int len = lens[b];
    int base = chunk * CHUNK;
    int pidx = (b * NCHUNK + chunk) * HH;
    if (base >= len) {
        if (tid < HH) { m_p[pidx + tid] = NEGINF; s_p[pidx + tid] = 0.f; }
        return;
    }
    int nv = min(CHUNK, len - base);
    int ng = (nv + 31) >> 5;

    __shared__ __align__(16) unsigned short Tr[32][1032];  // row-major [t][e]
    __shared__ float Sred[16][HH][34];
    __shared__ unsigned short Pt[HH][40];
    __shared__ float sm_m[HH], sm_s[HH], sm_c[HH];

    if (tid < HH) { sm_m[tid] = NEGINF; sm_s[tid] = 0.f; }

    int hq = lane & 15, qg = lane >> 4;
    const unsigned short* wkb = wk16 + ((size_t)(b * HH + hq)) * DD + w * 64 + 8 * qg;
    bf16x8 afr0 = *(const bf16x8*)(wkb);
    bf16x8 afr1 = *(const bf16x8*)(wkb + 32);
    f32x4 zer = {0.f, 0.f, 0.f, 0.f};
    f32x4 ctxacc[4] = {zer, zer, zer, zer};
    float sbh = (tid < 512) ? sb[b * HH + (tid >> 5)] : 0.f;
    int st = tid >> 7;           // staging token within pass (0..7)
    int se = (tid & 127) * 8;    // staging e offset
    const size_t rowbase = (size_t)(b * LL + base);

    // prefetch registers
    bf16x8 pc[4];
    float4 pa[4], pb[4];
    auto LOADG = [&](int g) {
        if (MODE == 2) {
            const unsigned short* s0p = tcache + (rowbase + g * 32) * DD + se;
#pragma unroll
            for (int p = 0; p < 4; ++p)
                pc[p] = *(const bf16x8*)(s0p + (size_t)(p * 8 + st) * DD);
        } else {
            const float* s0p = toks + (rowbase + g * 32) * DD + se;
#pragma unroll
            for (int p = 0; p < 4; ++p) {
                const float* sp = s0p + (size_t)(p * 8 + st) * DD;
                pa[p] = *(const float4*)sp;
                pb[p] = *(const float4*)(sp + 4);
            }
        }
    };
    LOADG(0);
    __syncthreads();

    for (int g = 0; g < ng; ++g) {
        int t0 = g * 32;
        // ---- write prefetched group to LDS (and cache for MODE 1)
        if (MODE == 2) {
#pragma unroll
            for (int p = 0; p < 4; ++p)
                *(bf16x8*)&Tr[p * 8 + st][se] = pc[p];
        } else {
#pragma unroll
            for (int p = 0; p < 4; ++p) {
                bf16x8 v;
                v[0] = f2b(pa[p].x); v[1] = f2b(pa[p].y);
                v[2] = f2b(pa[p].z); v[3] = f2b(pa[p].w);
                v[4] = f2b(pb[p].x); v[5] = f2b(pb[p].y);
                v[6] = f2b(pb[p].z); v[7] = f2b(pb[p].w);
                *(bf16x8*)&Tr[p * 8 + st][se] = v;
                if (MODE == 1)
                    *(bf16x8*)(tcache + (rowbase + t0 + p * 8 + st) * DD + se) = v;
            }
        }
        if (g + 1 < ng) LOADG(g + 1);   // issue next group's loads early
        __syncthreads();
        // ---- scores: b128 row reads
        f32x4 s0 = zer, s1 = zer;
        {
            int eb = w * 64 + 8 * qg;
            s0 = __builtin_amdgcn_mfma_f32_16x16x32_bf16(afr0, *(const bf16x8*)&Tr[hq][eb], s0, 0, 0, 0);
            s0 = __builtin_amdgcn_mfma_f32_16x16x32_bf16(afr1, *(const bf16x8*)&Tr[hq][eb + 32], s0, 0, 0, 0);
            s1 = __builtin_amdgcn_mfma_f32_16x16x32_bf16(afr0, *(const bf16x8*)&Tr[16 + hq][eb], s1, 0, 0, 0);
            s1 = __builtin_amdgcn_mfma_f32_16x16x32_bf16(afr1, *(const bf16x8*)&Tr[16 + hq][eb + 32], s1, 0, 0, 0);
        }
#pragma unroll
        for (int r = 0; r < 4; ++r) {
            Sred[w][qg * 4 + r][hq] = s0[r];
            Sred[w][qg * 4 + r][16 + hq] = s1[r];
        }
        __syncthreads();
        // ---- cross-wave reduce + online softmax
        if (tid < 512) {
            int h = tid >> 5, t = tid & 31;
            float s = 0.f;
#pragma unroll
            for (int ww = 0; ww < 16; ++ww) s += Sred[ww][h][t];
            s = (s + sbh) * 0.125f;
            bool valid = (t0 + t) < nv;
            if (!valid) s = NEGINF;
            float tm = s;
#pragma unroll
            for (int off = 16; off; off >>= 1) tm = fmaxf(tm, __shfl_xor(tm, off, 32));
            float oldm = sm_m[h];
            float newm = fmaxf(oldm, tm);
            float pv = valid ? __expf(s - newm) : 0.f;
            float ps = pv;
#pragma unroll
            for (int off = 16; off; off >>= 1) ps += __shfl_xor(ps, off, 32);
            if (t == 0) {
                float corr = __expf(oldm - newm);
                sm_c[h] = corr;
                sm_m[h] = newm;
                sm_s[h] = sm_s[h] * corr + ps;
            }
            Pt[h][t] = f2b(pv);
        }
        __syncthreads();
        // ---- ctx accumulate
        {
            float cr[4];
#pragma unroll
            for (int r = 0; r < 4; ++r) cr[r] = sm_c[qg * 4 + r];
            bf16x8 pafr;
            ushort4 pa0 = *(const ushort4*)&Pt[hq][8 * qg];
            ushort4 pa1 = *(const ushort4*)&Pt[hq][8 * qg + 4];
            pafr[0] = pa0.x; pafr[1] = pa0.y; pafr[2] = pa0.z; pafr[3] = pa0.w;
            pafr[4] = pa1.x; pafr[5] = pa1.y; pafr[6] = pa1.z; pafr[7] = pa1.w;
#pragma unroll
            for (int et = 0; et < 4; ++et) {
#pragma unroll
                for (int r = 0; r < 4; ++r) ctxacc[et][r] *= cr[r];
                bf16x8 bfr;
                int ec = w * 64 + et * 16 + hq;
#pragma unroll
                for (int i = 0; i < 8; ++i) bfr[i] = (short)Tr[8 * qg + i][ec];
                ctxacc[et] = __builtin_amdgcn_mfma_f32_16x16x32_bf16(pafr, bfr, ctxacc[et], 0, 0, 0);
            }
        }
        __syncthreads();
    }
    if (tid < HH) { m_p[pidx + tid] = sm_m[tid]; s_p[pidx + tid] = sm_s[tid]; }
#pragma unroll
    for (int et = 0; et < 4; ++et)
#pragma unroll
        for (int r = 0; r < 4; ++r) {
            int h = qg * 4 + r, e = w * 64 + et * 16 + hq;
            ctx_p[((size_t)pidx + h) * DD + e] = ctxacc[et][r];
        }
}

extern "C" void kernel_launch(void* const* d_in, const int* in_sizes, int n_in,
                              void* d_out, int out_size, void* d_ws, size_t ws_size,
                              hipStream_t stream) {
    const float* toks  = (const float*)d_in[0];
    const int*   lens  = (const int*)d_in[1];
    const float* qt    = (const float*)d_in[2];
    const float* Wq    = (const float*)d_in[3];
    const float* bq    = (const float*)d_in[4];
    const float* Wk    = (const float*)d_in[5];
    const float* bk    = (const float*)d_in[6];
    const float* Wv    = (const float*)d_in[7];
    const float* bv    = (const float*)d_in[8];
    const float* Wo    = (const float*)d_in[9];
    const float* bo    = (const float*)d_in[10];
    const float* gamma = (const float*)d_in[11];
    const float* beta  = (const float*)d_in[12];
    float* out = (float*)d_out;
    float* ws  = (float*)d_ws;

    // ws layout (float offsets)
    float* ctx_p = ws;                       // 4194304
    float* m_p   = ws + 4194304;             // 4096
    float* s_p   = ws + 4198400;             // 4096
    float* pvp   = ws + 4202496;             // 1048576 (32 partials)
    float* op    = ws + 5251072;             // 262144  (8 partials)
    float* qp    = ws + 5513216;             // 262144  (8 partials)
    float* oraw  = ws + 5775360;             // 32768
    float* stats = ws + 5808128;             // 64
    float* sbuf  = ws + 5808192;             // 512
    unsigned short* wk16 = (unsigned short*)(ws + 5808704);  // 524288 u16
    const size_t base_floats = 6070848;
    unsigned short* tcache = (unsigned short*)(ws + base_floats);
    const size_t need_cache = base_floats * 4 + (size_t)BB * LL * DD * 2;
    const bool use_cache = (ws_size >= need_cache);

    // prologue: q0 partials (broadcast qt) -> wk layer 0 (inline combine)
    k_gemv<0, 8><<<128, 256, 0, stream>>>(qt, nullptr, nullptr, nullptr,
            nullptr, nullptr, nullptr, nullptr, nullptr, Wq, qp);
    k_wk<<<256, 256, 0, stream>>>(qp, bq, Wk, bk, wk16, sbuf);

    for (int i = 0; i < NL; ++i) {
        if (use_cache) {
            if (i == 0)
                k_attn<1><<<256, 1024, 0, stream>>>(toks, tcache, lens, wk16,
                        sbuf, ctx_p, m_p, s_p);
            else
                k_attn<2><<<256, 1024, 0, stream>>>(toks, tcache, lens, wk16,
                        sbuf, ctx_p, m_p, s_p);
        } else {
            k_attn<0><<<256, 1024, 0, stream>>>(toks, tcache, lens, wk16,
                    sbuf, ctx_p, m_p, s_p);
        }
        const float* Wv_i = Wv + (size_t)i * DD * DD;
        const float* Wo_i = Wo + (size_t)i * DD * DD;
        // pv partials (KS=32): chunk-combined ctx @ Wv
        k_gemv<3, 32><<<512, 256, 0, stream>>>(nullptr, nullptr, nullptr, nullptr,
                nullptr, nullptr, ctx_p, m_p, s_p, Wv_i, pvp);
        // o partials (KS=8): (sum pv + bv) @ Wo
        k_gemv<2, 8><<<128, 256, 0, stream>>>(nullptr, nullptr, nullptr, nullptr,
                pvp, bv + i * DD, nullptr, nullptr, nullptr, Wo_i, op);
        // combine + bo -> oraw, LN stats
        k_stats<<<32, 1024, 0, stream>>>(op, bo + i * DD, oraw, stats);
        if (i == NL - 1) {
            k_final<<<128, 256, 0, stream>>>(oraw, stats, gamma + i * DD,
                    beta + i * DD, out);
        } else {
            // q_{i+1} partials (KS=8) = LN(oraw) @ Wq_{i+1}; wk combines inline
            k_gemv<1, 8><<<128, 256, 0, stream>>>(oraw, stats, gamma + i * DD,
                    beta + i * DD, nullptr, nullptr, nullptr, nullptr, nullptr,
                    Wq + (size_t)(i + 1) * DD * DD, qp);
            k_wk<<<256, 256, 0, stream>>>(qp, bq + (i + 1) * DD,
                    Wk + (size_t)(i + 1) * DD * DD, bk + (i + 1) * DD,
                    wk16, sbuf);
        }
    }
}

// Round 6
// 353.884 us; speedup vs baseline: 1.1377x; 1.1377x over previous
//
#include <hip/hip_runtime.h>
#include <hip/hip_bf16.h>
#include <cstdint>
#include <cstddef>

#define BB 32
#define LL 2048
#define DD 1024
#define HH 16
#define HDIM 64
#define NL 4
#define NCHUNK 8
#define CHUNK 256
#define NEGINF -1e30f
#define PKS 16         // K-splits for all epilogue GEMVs

typedef __attribute__((ext_vector_type(8))) short bf16x8;
typedef __attribute__((ext_vector_type(4))) float f32x4;

__device__ __forceinline__ unsigned short f2b(float x) {
    union { float f; unsigned int u; } v; v.f = x;
    unsigned int r = (v.u + 0x7FFFu + ((v.u >> 16) & 1u)) >> 16;
    return (unsigned short)r;
}
__device__ __forceinline__ float b2f(unsigned short u) {
    union { unsigned int u; float f; } v; v.u = ((unsigned int)u) << 16;
    return v.f;
}

// ---------------- split-K GEMV partials: part[ks][b][c] = X[b, e0:e0+64] @ W[e0:e0+64, c]
// SRC 0: X[b][e] = Xg[e]                      (broadcast qt)
// SRC 1: X = (Xg - mu)*rstd*gamma + beta      (LayerNorm applied on the fly)
// SRC 2: X = bias + sum_{j2<16} parts_in      (combine pv partials)
// SRC 3: X = sum_c8 wgt[b][c8]*ctx16[...]     (softmax chunk combine; head = ct)
template<int SRC>
__global__ __launch_bounds__(256) void k_gemv(
        const float* __restrict__ Xg,
        const float* __restrict__ stats, const float* __restrict__ gamma,
        const float* __restrict__ beta,
        const float* __restrict__ parts_in, const float* __restrict__ bias_in,
        const unsigned short* __restrict__ ctx16, const float* __restrict__ m_p,
        const float* __restrict__ s_p,
        const float* __restrict__ W, float* __restrict__ outp) {
    constexpr int KL = DD / PKS;   // 64
    int bid = blockIdx.x, tid = threadIdx.x;
    int ct = bid & 15, ks = bid >> 4;
    int e0 = ks * KL;
    __shared__ float Xs[BB][KL];
    __shared__ float wgtS[BB][NCHUNK];
    __shared__ float mgS[BB], SgS[BB];
    if (SRC == 3) {
        if (tid < BB) {
            int b = tid; float m = NEGINF;
            for (int c8 = 0; c8 < NCHUNK; ++c8)
                m = fmaxf(m, m_p[(b * NCHUNK + c8) * HH + ct]);
            float S = 0.f;
            for (int c8 = 0; c8 < NCHUNK; ++c8)
                S += s_p[(b * NCHUNK + c8) * HH + ct] *
                     __expf(m_p[(b * NCHUNK + c8) * HH + ct] - m);
            mgS[b] = m; SgS[b] = S;
        }
        __syncthreads();
        {
            int b = tid >> 3, c8 = tid & 7;
            wgtS[b][c8] = __expf(m_p[(b * NCHUNK + c8) * HH + ct] - mgS[b]) / SgS[b];
        }
        __syncthreads();
    }
    // stage Xs[32][64] (2048 elems, 8 per thread)
#pragma unroll
    for (int j = 0; j < 8; ++j) {
        int i = tid + j * 256;
        int b = i >> 6, k = i & 63;
        float x;
        if (SRC == 0) {
            x = Xg[e0 + k];
        } else if (SRC == 1) {
            float mu = stats[b * 2], rstd = stats[b * 2 + 1];
            x = (Xg[(size_t)b * DD + e0 + k] - mu) * rstd * gamma[e0 + k] + beta[e0 + k];
        } else if (SRC == 2) {
            x = bias_in[e0 + k];
#pragma unroll
            for (int j2 = 0; j2 < PKS; ++j2)
                x += parts_in[((size_t)(j2 * BB) + b) * DD + e0 + k];
        } else {
            x = 0.f;
#pragma unroll
            for (int c8 = 0; c8 < NCHUNK; ++c8)
                x += wgtS[b][c8] *
                     b2f(ctx16[(((size_t)(b * NCHUNK + c8)) * HH + ct) * DD + e0 + k]);
        }
        Xs[b][k] = x;
    }
    __syncthreads();
    int col = tid & 63, bg = tid >> 6;
    int c = ct * 64 + col;
    float acc[8] = {0.f, 0.f, 0.f, 0.f, 0.f, 0.f, 0.f, 0.f};
    for (int k = 0; k < KL; k += 4) {
        float w0 = W[(size_t)(e0 + k) * DD + c];
        float w1 = W[(size_t)(e0 + k + 1) * DD + c];
        float w2 = W[(size_t)(e0 + k + 2) * DD + c];
        float w3 = W[(size_t)(e0 + k + 3) * DD + c];
#pragma unroll
        for (int bb = 0; bb < 8; ++bb) {
            const float4 xv = *(const float4*)&Xs[bg * 8 + bb][k];
            acc[bb] += xv.x * w0 + xv.y * w1 + xv.z * w2 + xv.w * w3;
        }
    }
#pragma unroll
    for (int bb = 0; bb < 8; ++bb)
        outp[((size_t)(ks * BB) + bg * 8 + bb) * DD + c] = acc[bb];
}

// ---------------- combine o partials + bo -> oraw + LN stats (and final LN if LAST)
template<int LAST>
__global__ __launch_bounds__(1024) void k_stats(const float* __restrict__ parts,
        const float* __restrict__ bo, const float* __restrict__ gamma,
        const float* __restrict__ beta, float* __restrict__ oraw,
        float* __restrict__ stats, float* __restrict__ outp) {
    int b = blockIdx.x, c = threadIdx.x;
    float v = bo[c];
#pragma unroll
    for (int ks = 0; ks < PKS; ++ks)
        v += parts[((size_t)(ks * BB) + b) * DD + c];
    if (!LAST) oraw[(size_t)b * DD + c] = v;
    float s1 = v, s2 = v * v;
#pragma unroll
    for (int off = 32; off; off >>= 1) {
        s1 += __shfl_xor(s1, off);
        s2 += __shfl_xor(s2, off);
    }
    __shared__ float r1[16], r2[16];
    __shared__ float smu, srs;
    int w = c >> 6;
    if ((c & 63) == 0) { r1[w] = s1; r2[w] = s2; }
    __syncthreads();
    if (c == 0) {
        float a = 0.f, q = 0.f;
#pragma unroll
        for (int i = 0; i < 16; ++i) { a += r1[i]; q += r2[i]; }
        float mu = a / (float)DD, var = q / (float)DD - mu * mu;
        float rs = rsqrtf(var + 1e-5f);
        smu = mu; srs = rs;
        stats[b * 2] = mu;
        stats[b * 2 + 1] = rs;
    }
    __syncthreads();
    if (LAST)
        outp[(size_t)b * DD + c] = (v - smu) * srs * gamma[c] + beta[c];
}

// ---------------- wk[b,h,e] = Wk[e, h*64:+64] . qh[b, h*64:+64] (bf16) + sbuf
// qh combined inline from qp partials (PKS) + bq. grid 256: h(16) x et(16)
__global__ __launch_bounds__(256) void k_wk(const float* __restrict__ qp,
        const float* __restrict__ bq,
        const float* __restrict__ Wk, const float* __restrict__ bk,
        unsigned short* __restrict__ wk16, float* __restrict__ sb) {
    int h = blockIdx.x >> 4, et = blockIdx.x & 15;
    int tid = threadIdx.x;
    __shared__ float qs[BB][HDIM + 1];
    for (int i = tid; i < BB * HDIM; i += 256) {
        int bb = i >> 6, d = i & 63;
        float v = bq[h * HDIM + d];
#pragma unroll
        for (int ks = 0; ks < PKS; ++ks)
            v += qp[((size_t)(ks * BB + bb)) * DD + h * HDIM + d];
        qs[bb][d] = v;
    }
    __syncthreads();
    int b = tid & 31, eo = tid >> 5;   // eo: 0..7
    for (int k = 0; k < 8; ++k) {
        int e = et * 64 + eo * 8 + k;
        const float* wrow = Wk + (size_t)e * DD + h * HDIM;
        float acc = 0.f;
#pragma unroll
        for (int d = 0; d < HDIM; ++d) acc += qs[b][d] * wrow[d];
        wk16[((size_t)(b * HH + h)) * DD + e] = f2b(acc);
    }
    if (et == 0 && tid < BB) {
        float acc = 0.f;
#pragma unroll
        for (int d = 0; d < HDIM; ++d) acc += qs[tid][d] * bk[h * HDIM + d];
        sb[tid * HH + h] = acc;
    }
}

// ---------------- main streaming attention pass (partial per (b, chunk))
// MODE 0: fp32 reads. MODE 1: fp32 reads + bf16 cache write. MODE 2: bf16 cache reads.
template<int MODE>
__global__ __launch_bounds__(1024) void k_attn(const float* __restrict__ toks,
        unsigned short* __restrict__ tcache,
        const int* __restrict__ lens, const unsigned short* __restrict__ wk16,
        const float* __restrict__ sb, unsigned short* __restrict__ ctx16,
        float* __restrict__ m_p, float* __restrict__ s_p) {
    int b = blockIdx.x >> 3, chunk = blockIdx.x & 7;
    int tid = threadIdx.x, lane = tid & 63, w = tid >> 6;
    int len = lens[b];
    int base = chunk * CHUNK;
    int pidx = (b * NCHUNK + chunk) * HH;
    if (base >= len) {
        if (tid < HH) { m_p[pidx + tid] = NEGINF; s_p[pidx + tid] = 0.f; }
        return;
    }
    int nv = min(CHUNK, len - base);

    __shared__ __align__(16) unsigned short Tr[32][1032];  // row-major [t][e]
    __shared__ float Sred[16][HH][34];
    __shared__ unsigned short Pt[HH][40];
    __shared__ float sm_m[HH], sm_s[HH], sm_c[HH];

    if (tid < HH) { sm_m[tid] = NEGINF; sm_s[tid] = 0.f; }

    int hq = lane & 15, qg = lane >> 4;
    const unsigned short* wkb = wk16 + ((size_t)(b * HH + hq)) * DD + w * 64 + 8 * qg;
    bf16x8 afr0 = *(const bf16x8*)(wkb);
    bf16x8 afr1 = *(const bf16x8*)(wkb + 32);
    f32x4 zer = {0.f, 0.f, 0.f, 0.f};
    f32x4 ctxacc[4] = {zer, zer, zer, zer};
    float sbh = (tid < 512) ? sb[b * HH + (tid >> 5)] : 0.f;
    int st = tid >> 7;           // staging token within pass (0..7)
    int se = (tid & 127) * 8;    // staging e offset
    __syncthreads();

    for (int g = 0; g < 8; ++g) {
        int t0 = g * 32;
        if (t0 >= nv) break;
        if (MODE == 2) {
            const unsigned short* srcr = tcache + ((size_t)(b * LL + base + t0)) * DD;
#pragma unroll
            for (int p = 0; p < 4; ++p) {
                int t = p * 8 + st;
                bf16x8 v = *(const bf16x8*)(srcr + (size_t)t * DD + se);
                *(bf16x8*)&Tr[t][se] = v;
            }
        } else {
            const float* srcr = toks + ((size_t)(b * LL + base + t0)) * DD;
#pragma unroll
            for (int p = 0; p < 4; ++p) {
                int t = p * 8 + st;
                const float* sp = srcr + (size_t)t * DD + se;
                float4 a0 = *(const float4*)sp;
                float4 a1 = *(const float4*)(sp + 4);
                bf16x8 v;
                v[0] = f2b(a0.x); v[1] = f2b(a0.y); v[2] = f2b(a0.z); v[3] = f2b(a0.w);
                v[4] = f2b(a1.x); v[5] = f2b(a1.y); v[6] = f2b(a1.z); v[7] = f2b(a1.w);
                *(bf16x8*)&Tr[t][se] = v;
                if (MODE == 1)
                    *(bf16x8*)(tcache + ((size_t)(b * LL + base + t0 + t)) * DD + se) = v;
            }
        }
        __syncthreads();
        f32x4 s0 = zer, s1 = zer;
        {
            int eb = w * 64 + 8 * qg;
            s0 = __builtin_amdgcn_mfma_f32_16x16x32_bf16(afr0, *(const bf16x8*)&Tr[hq][eb], s0, 0, 0, 0);
            s0 = __builtin_amdgcn_mfma_f32_16x16x32_bf16(afr1, *(const bf16x8*)&Tr[hq][eb + 32], s0, 0, 0, 0);
            s1 = __builtin_amdgcn_mfma_f32_16x16x32_bf16(afr0, *(const bf16x8*)&Tr[16 + hq][eb], s1, 0, 0, 0);
            s1 = __builtin_amdgcn_mfma_f32_16x16x32_bf16(afr1, *(const bf16x8*)&Tr[16 + hq][eb + 32], s1, 0, 0, 0);
        }
#pragma unroll
        for (int r = 0; r < 4; ++r) {
            Sred[w][qg * 4 + r][hq] = s0[r];
            Sred[w][qg * 4 + r][16 + hq] = s1[r];
        }
        __syncthreads();
        if (tid < 512) {
            int h = tid >> 5, t = tid & 31;
            float s = 0.f;
#pragma unroll
            for (int ww = 0; ww < 16; ++ww) s += Sred[ww][h][t];
            s = (s + sbh) * 0.125f;
            bool valid = (t0 + t) < nv;
            if (!valid) s = NEGINF;
            float tm = s;
#pragma unroll
            for (int off = 16; off; off >>= 1) tm = fmaxf(tm, __shfl_xor(tm, off, 32));
            float oldm = sm_m[h];
            float newm = fmaxf(oldm, tm);
            float pv = valid ? __expf(s - newm) : 0.f;
            float ps = pv;
#pragma unroll
            for (int off = 16; off; off >>= 1) ps += __shfl_xor(ps, off, 32);
            if (t == 0) {
                float corr = __expf(oldm - newm);
                sm_c[h] = corr;
                sm_m[h] = newm;
                sm_s[h] = sm_s[h] * corr + ps;
            }
            Pt[h][t] = f2b(pv);
        }
        __syncthreads();
        {
            float cr[4];
#pragma unroll
            for (int r = 0; r < 4; ++r) cr[r] = sm_c[qg * 4 + r];
            bf16x8 pafr;
            ushort4 pa0 = *(const ushort4*)&Pt[hq][8 * qg];
            ushort4 pa1 = *(const ushort4*)&Pt[hq][8 * qg + 4];
            pafr[0] = pa0.x; pafr[1] = pa0.y; pafr[2] = pa0.z; pafr[3] = pa0.w;
            pafr[4] = pa1.x; pafr[5] = pa1.y; pafr[6] = pa1.z; pafr[7] = pa1.w;
#pragma unroll
            for (int et = 0; et < 4; ++et) {
#pragma unroll
                for (int r = 0; r < 4; ++r) ctxacc[et][r] *= cr[r];
                bf16x8 bfr;
                int ec = w * 64 + et * 16 + hq;
#pragma unroll
                for (int i = 0; i < 8; ++i) bfr[i] = (short)Tr[8 * qg + i][ec];
                ctxacc[et] = __builtin_amdgcn_mfma_f32_16x16x32_bf16(pafr, bfr, ctxacc[et], 0, 0, 0);
            }
        }
        __syncthreads();
    }
    if (tid < HH) { m_p[pidx + tid] = sm_m[tid]; s_p[pidx + tid] = sm_s[tid]; }
#pragma unroll
    for (int et = 0; et < 4; ++et)
#pragma unroll
        for (int r = 0; r < 4; ++r) {
            int h = qg * 4 + r, e = w * 64 + et * 16 + hq;
            ctx16[((size_t)pidx + h) * DD + e] = f2b(ctxacc[et][r]);
        }
}

extern "C" void kernel_launch(void* const* d_in, const int* in_sizes, int n_in,
                              void* d_out, int out_size, void* d_ws, size_t ws_size,
                              hipStream_t stream) {
    const float* toks  = (const float*)d_in[0];
    const int*   lens  = (const int*)d_in[1];
    const float* qt    = (const float*)d_in[2];
    const float* Wq    = (const float*)d_in[3];
    const float* bq    = (const float*)d_in[4];
    const float* Wk    = (const float*)d_in[5];
    const float* bk    = (const float*)d_in[6];
    const float* Wv    = (const float*)d_in[7];
    const float* bv    = (const float*)d_in[8];
    const float* Wo    = (const float*)d_in[9];
    const float* bo    = (const float*)d_in[10];
    const float* gamma = (const float*)d_in[11];
    const float* beta  = (const float*)d_in[12];
    float* out = (float*)d_out;
    float* ws  = (float*)d_ws;

    // ws layout (float offsets)
    unsigned short* ctx16 = (unsigned short*)ws;   // 32*8*16*1024 u16 = 2097152 floats
    float* m_p   = ws + 2097152;             // 4096
    float* s_p   = ws + 2101248;             // 4096
    float* pvp   = ws + 2105344;             // 524288 (16 partials)
    float* op    = ws + 2629632;             // 524288
    float* qp    = ws + 3153920;             // 524288
    float* oraw  = ws + 3678208;             // 32768
    float* stats = ws + 3710976;             // 64
    float* sbuf  = ws + 3711040;             // 512
    unsigned short* wk16 = (unsigned short*)(ws + 3711552);  // 524288 u16
    const size_t base_floats = 3973696;
    unsigned short* tcache = (unsigned short*)(ws + base_floats);
    const size_t need_cache = base_floats * 4 + (size_t)BB * LL * DD * 2;
    const bool use_cache = (ws_size >= need_cache);

    // prologue: q0 partials (broadcast qt) -> wk layer 0 (inline combine)
    k_gemv<0><<<256, 256, 0, stream>>>(qt, nullptr, nullptr, nullptr,
            nullptr, nullptr, nullptr, nullptr, nullptr, Wq, qp);
    k_wk<<<256, 256, 0, stream>>>(qp, bq, Wk, bk, wk16, sbuf);

    for (int i = 0; i < NL; ++i) {
        if (use_cache) {
            if (i == 0)
                k_attn<1><<<256, 1024, 0, stream>>>(toks, tcache, lens, wk16,
                        sbuf, ctx16, m_p, s_p);
            else
                k_attn<2><<<256, 1024, 0, stream>>>(toks, tcache, lens, wk16,
                        sbuf, ctx16, m_p, s_p);
        } else {
            k_attn<0><<<256, 1024, 0, stream>>>(toks, tcache, lens, wk16,
                    sbuf, ctx16, m_p, s_p);
        }
        const float* Wv_i = Wv + (size_t)i * DD * DD;
        const float* Wo_i = Wo + (size_t)i * DD * DD;
        // pv partials (PKS=16): chunk-combined ctx @ Wv
        k_gemv<3><<<256, 256, 0, stream>>>(nullptr, nullptr, nullptr, nullptr,
                nullptr, nullptr, ctx16, m_p, s_p, Wv_i, pvp);
        // o partials: (sum pv + bv) @ Wo
        k_gemv<2><<<256, 256, 0, stream>>>(nullptr, nullptr, nullptr, nullptr,
                pvp, bv + i * DD, nullptr, nullptr, nullptr, Wo_i, op);
        if (i == NL - 1) {
            // combine + bo + LN -> out (fused final)
            k_stats<1><<<32, 1024, 0, stream>>>(op, bo + i * DD, gamma + i * DD,
                    beta + i * DD, oraw, stats, out);
        } else {
            // combine + bo -> oraw, LN stats
            k_stats<0><<<32, 1024, 0, stream>>>(op, bo + i * DD, gamma + i * DD,
                    beta + i * DD, oraw, stats, out);
            // q_{i+1} partials = LN(oraw) @ Wq_{i+1}; wk combines inline
            k_gemv<1><<<256, 256, 0, stream>>>(oraw, stats, gamma + i * DD,
                    beta + i * DD, nullptr, nullptr, nullptr, nullptr, nullptr,
                    Wq + (size_t)(i + 1) * DD * DD, qp);
            k_wk<<<256, 256, 0, stream>>>(qp, bq + (i + 1) * DD,
                    Wk + (size_t)(i + 1) * DD * DD, bk + (i + 1) * DD,
                    wk16, sbuf);
        }
    }
}